// Round 3
// baseline (281.525 us; speedup 1.0000x reference)
//
#include <hip/hip_runtime.h>
#include <math.h>

#define EMBED 1024
#define NHEAD 16
#define HDIM  64
#define SEQT  2048
#define BATCH 4

typedef __bf16 bf16x4 __attribute__((ext_vector_type(4)));
typedef __bf16 bf16x8 __attribute__((ext_vector_type(8)));
typedef float  f32x4  __attribute__((ext_vector_type(4)));

#define AS1 __attribute__((address_space(1)))
#define AS3 __attribute__((address_space(3)))
// async global->LDS, 16B per lane (guide §5: width=16, m97-verified)
#define GLD_LDS16(gp, lp) __builtin_amdgcn_global_load_lds( \
    (const AS1 unsigned int*)(gp), (AS3 unsigned int*)(lp), 16, 0, 0)

// log2(e) / sqrt(HDIM): folded into Q at QKV-epilogue so scores are exp2-ready
#define QSCALE 0.180336880f

// native cast (v_cvt_pk_bf16_f32 on gfx950)
__device__ __forceinline__ unsigned short f2bf_hw(float f) {
    union { __bf16 h; unsigned short u; } c; c.h = (__bf16)f; return c.u;
}

// one launch converts x, W_qkv, W_proj (fp32 -> bf16), in float4 units
__global__ __launch_bounds__(256)
void cvt_all(const float* __restrict__ x, const float* __restrict__ wq,
             const float* __restrict__ wp,
             unsigned short* __restrict__ xb, unsigned short* __restrict__ wqb,
             unsigned short* __restrict__ wpb)
{
    const int N1 = 2097152;            // 8192*1024/4
    const int N2 = 786432;             // 3*1024*1024/4
    int i = blockIdx.x * 256 + threadIdx.x;
    const float4* src; ushort4* dst; int j;
    if (i < N1)            { src = (const float4*)x;  dst = (ushort4*)xb;  j = i; }
    else if (i < N1 + N2)  { src = (const float4*)wq; dst = (ushort4*)wqb; j = i - N1; }
    else                   { src = (const float4*)wp; dst = (ushort4*)wpb; j = i - N1 - N2; }
    float4 v = src[j];
    ushort4 o;
    o.x = f2bf_hw(v.x); o.y = f2bf_hw(v.y); o.z = f2bf_hw(v.z); o.w = f2bf_hw(v.w);
    dst[j] = o;
}

// ---------------- bf16 MFMA GEMM, 256x256 / BK=64 / m201 8-phase schedule ------
// C[m,n] = sum_k A[m,k]*Bw[n,k] + bias[n].  512 thr = 8 waves (2M x 4N), per-wave
// 128x64 output (acc 8x4 of 16x16x32) — the geometry where LDS-read BW matches
// the matrix pipe (24 ds_read_b128 / 64 MFMA per K-tile per wave).
// LDS 128 KiB: 2 dbuf x (A 32KB + B 32KB), QUADRANT-MAJOR row permutation:
//   A lds_row = qm*128 + wm*64 + u   (global m = m0 + wm*128 + qm*64 + u)
//   B lds_row = qn*128 + wn*32 + u   (global n = n0 + wn*64 + qn*32 + u)
// so each phase reads only half-tiles already landed. Legal because gld_lds's
// GLOBAL source is per-lane (rule #21); LDS dest stays linear.
// Per K-tile: 4 phases (reads 12/4/8/4 + 16 MFMA each, template counts);
// 1 half-tile (2 gld_lds) staged per phase in need-order A0,B0,B1,A1;
// 3x vmcnt(4) per tile (ends of ph1, ph2, ph4) — COUNTED, never drained:
//   steady state 4-8 loads in flight; each wait sits before the phase-closing
//   barrier so cross-wave LDS visibility is barrier-ordered.
// T2 swizzle: 16B slot ^= (lds_row & 7) on reads, inverse pre-applied to the
// global source slot (R1/R2-verified: SQ_LDS_BANK_CONFLICT = 0).
#define BAR do { __builtin_amdgcn_sched_barrier(0); \
                 __builtin_amdgcn_s_barrier(); \
                 __builtin_amdgcn_sched_barrier(0); } while (0)

template<int MODE>
__global__ __launch_bounds__(512, 2)
void gemm_bt_m201(const unsigned short* __restrict__ A, const unsigned short* __restrict__ Bw,
                  const float* __restrict__ bias,
                  void* out0, void* out1, void* out2,
                  int M, int N)
{
    const int K = 1024;                 // both GEMMs have K=1024
    const int T = 16;                   // K / 64
    __shared__ __align__(16) unsigned short Asm[2][256 * 64];   // 2 x 32 KB
    __shared__ __align__(16) unsigned short Bsm[2][256 * 64];   // 2 x 32 KB

    const int tid  = threadIdx.x;
    const int lane = tid & 63;
    const int wave = tid >> 6;
    const int wm = wave >> 2, wn = wave & 3;          // 2M x 4N wave grid
    const int col = lane & 15, quad = lane >> 4;

    // T1: XCD chunk swizzle on the linear block id (nwg % 8 == 0 for both grids)
    const int gx = gridDim.x;
    const int nwg = gx * gridDim.y;
    int wg = blockIdx.y * gx + blockIdx.x;
    wg = (wg & 7) * (nwg >> 3) + (wg >> 3);
    const long m0 = (long)(wg / gx) * 256;
    const long n0 = (long)(wg % gx) * 256;

    f32x4 acc[8][4];
#pragma unroll
    for (int mi = 0; mi < 8; mi++)
#pragma unroll
        for (int ni = 0; ni < 4; ni++) acc[mi][ni] = (f32x4){0.f, 0.f, 0.f, 0.f};

    // staging geometry: per gld_lds a wave-group covers 64 lds rows; thread ->
    // lds row (tid>>3), 16B slot (tid&7). Source slot pre-swizzled (^ row&7).
    const int srow  = tid >> 3;                // 0..63
    const int sslot = tid & 7;
    const int gslot = sslot ^ (srow & 7);
    // A source base: global row m0 + srow (r-group adds 128, qm adds 64)
    const unsigned short* Agb = A + (m0 + srow) * (long)K + gslot * 8;
    // B source base: global row n0 + (srow>>5)*64 + (srow&31) (r adds 128, qn adds 32)
    const unsigned short* Bgb = Bw + (n0 + (srow >> 5) * 64 + (srow & 31)) * (long)K + gslot * 8;

#define STAGE_A(b, t_, qm_) do { \
    GLD_LDS16(Agb + ((qm_) * 64      ) * (long)K + (t_) * 64, &Asm[b][((qm_) * 128     ) * 64] + tid * 8); \
    GLD_LDS16(Agb + ((qm_) * 64 + 128) * (long)K + (t_) * 64, &Asm[b][((qm_) * 128 + 64) * 64] + tid * 8); \
  } while (0)
#define STAGE_B(b, t_, qn_) do { \
    GLD_LDS16(Bgb + ((qn_) * 32      ) * (long)K + (t_) * 64, &Bsm[b][((qn_) * 128     ) * 64] + tid * 8); \
    GLD_LDS16(Bgb + ((qn_) * 32 + 128) * (long)K + (t_) * 64, &Bsm[b][((qn_) * 128 + 64) * 64] + tid * 8); \
  } while (0)

    // swizzled fragment reads (quadrant-major rows); row&7 == col&7 for all rows
#define LOAD_A(qm_) do { _Pragma("unroll") for (int i_ = 0; i_ < 4; i_++) { \
        const int ra_ = (qm_) * 128 + wm * 64 + i_ * 16 + col; \
        const int rx_ = col & 7; \
        af[i_][0] = *(const bf16x8*)&Ac[ra_ * 64 + ((quad    ) ^ rx_) * 8]; \
        af[i_][1] = *(const bf16x8*)&Ac[ra_ * 64 + ((quad + 4) ^ rx_) * 8]; \
    } } while (0)

#define LOAD_B(qn_) do { _Pragma("unroll") for (int j_ = 0; j_ < 2; j_++) { \
        const int rb_ = (qn_) * 128 + wn * 32 + j_ * 16 + col; \
        const int rx_ = col & 7; \
        bfv[j_][0] = *(const bf16x8*)&Bc[rb_ * 64 + ((quad    ) ^ rx_) * 8]; \
        bfv[j_][1] = *(const bf16x8*)&Bc[rb_ * 64 + ((quad + 4) ^ rx_) * 8]; \
    } } while (0)

#define MFMA_Q(qm_, qn_) do { __builtin_amdgcn_s_setprio(1); \
    _Pragma("unroll") for (int i_ = 0; i_ < 4; i_++) \
    _Pragma("unroll") for (int j_ = 0; j_ < 2; j_++) { \
        acc[(qm_) * 4 + i_][(qn_) * 2 + j_] = __builtin_amdgcn_mfma_f32_16x16x32_bf16( \
            af[i_][0], bfv[j_][0], acc[(qm_) * 4 + i_][(qn_) * 2 + j_], 0, 0, 0); \
        acc[(qm_) * 4 + i_][(qn_) * 2 + j_] = __builtin_amdgcn_mfma_f32_16x16x32_bf16( \
            af[i_][1], bfv[j_][1], acc[(qm_) * 4 + i_][(qn_) * 2 + j_], 0, 0, 0); \
    } \
    __builtin_amdgcn_s_setprio(0); } while (0)

    // prologue: tile 0's 4 half-tiles in need-order; wait oldest 2 (A0,B0)
    STAGE_A(0, 0, 0); STAGE_B(0, 0, 0); STAGE_B(0, 0, 1); STAGE_A(0, 0, 1);
    __builtin_amdgcn_s_waitcnt(0x0F74);   // vmcnt(4): A0,B0 landed; B1,A1 in flight
    BAR;

#pragma unroll 2
    for (int t = 0; t < T; t++) {
        const int cur = t & 1, nb = cur ^ 1, nt = t + 1;
        const unsigned short* Ac = &Asm[cur][0];
        const unsigned short* Bc = &Bsm[cur][0];
        bf16x8 af[4][2], bfv[2][2];

        // ph1: quadrant (0,0) — A half0 (8 rd) + B half0 (4 rd); stage A0(t+1)
        LOAD_A(0); LOAD_B(0);
        if (nt < T) STAGE_A(nb, nt, 0);
        BAR;
        MFMA_Q(0, 0);
        if (nt < T) __builtin_amdgcn_s_waitcnt(0x0F74);  // B1(t) landed
        else        __builtin_amdgcn_s_waitcnt(0x0F72);  // tail: vmcnt(2)
        BAR;
        // ph2: quadrant (0,1) — B half1 (4 rd); stage B0(t+1)
        LOAD_B(1);
        if (nt < T) STAGE_B(nb, nt, 0);
        BAR;
        MFMA_Q(0, 1);
        if (nt < T) __builtin_amdgcn_s_waitcnt(0x0F74);  // A1(t) landed
        else        __builtin_amdgcn_s_waitcnt(0x0F70);  // tail: vmcnt(0)
        BAR;
        // ph3: quadrant (1,1) — A half1 (8 rd); stage B1(t+1)
        LOAD_A(1);
        if (nt < T) STAGE_B(nb, nt, 1);
        BAR;
        MFMA_Q(1, 1);
        BAR;
        // ph4: quadrant (1,0) — B half0 again (4 rd); stage A1(t+1)
        LOAD_B(0);
        if (nt < T) STAGE_A(nb, nt, 1);
        BAR;
        MFMA_Q(1, 0);
        if (nt < T) __builtin_amdgcn_s_waitcnt(0x0F74);  // A0,B0(t+1) landed
        BAR;
    }

#undef STAGE_A
#undef STAGE_B
#undef LOAD_A
#undef LOAD_B
#undef MFMA_Q

    // epilogue: C/D layout col=lane&15, row=quad*4+r (m89/m91-verified)
#pragma unroll
    for (int mi = 0; mi < 8; mi++) {
#pragma unroll
        for (int ni = 0; ni < 4; ni++) {
            long n = n0 + wn * 64 + ni * 16 + col;
            float bv = bias[n];
#pragma unroll
            for (int r = 0; r < 4; r++) {
                long m = m0 + wm * 128 + mi * 16 + quad * 4 + r;
                float v = acc[mi][ni][r] + bv;
                if (MODE == 0) {
                    ((float*)out0)[m * N + n] = v;
                } else {
                    int which = (int)(n >> 10);
                    int c = (int)(n & 1023);
                    int h = c >> 6, d = c & 63;
                    int b = (int)(m >> 11), t = (int)(m & 2047);
                    long bh = (long)(b * NHEAD + h);
                    if (which == 0)      ((unsigned short*)out0)[(bh * SEQT + t) * HDIM + d] = f2bf_hw(v * QSCALE);
                    else if (which == 1) ((unsigned short*)out1)[(bh * SEQT + t) * HDIM + d] = f2bf_hw(v);
                    else                 ((unsigned short*)out2)[(bh * HDIM + d) * SEQT + t] = f2bf_hw(v);
                }
            }
        }
    }
}

// ---------------- bf16 MFMA flash attention, v4 (unchanged) ----------------
// Q-tile 128; 4 waves × 32 q-rows. No-max softmax; S computed transposed
// (mfma(K,Q)) -> packed b64 P stores; P stored [q][k] for b128 PV A-frag reads.
#define PPAD 72

__global__ __launch_bounds__(256, 3)
void flash_attn_mfma4(const unsigned short* __restrict__ Qb,
                      const unsigned short* __restrict__ Kb,
                      const unsigned short* __restrict__ Vt,
                      unsigned short* __restrict__ Ob)
{
    __shared__ __align__(16) unsigned short P_lds[128 * PPAD];    // [q][k] 18432 B
    __shared__ __align__(16) unsigned short K_lds[2][64 * 64];    // 16 KB
    __shared__ __align__(16) unsigned short V_lds[2][64 * 64];    // 16 KB
    __shared__ __align__(16) float L_lds[128];                    // row sums

    const int tid  = threadIdx.x;
    const int lane = tid & 63;
    const int wave = tid >> 6;
    const int col  = lane & 15;
    const int quad = lane >> 4;

    const int idx = blockIdx.x;
    const int qt = 15 - (idx >> 6);      // longest blocks dispatched first
    const int hb = idx & 63;
    const int h = hb & 15, b = hb >> 4;
    const int q0 = qt * 128;
    const long bh = (long)(b * NHEAD + h);
    const unsigned short* Kbh = Kb + bh * SEQT * HDIM;
    const unsigned short* Vbh = Vt + bh * HDIM * SEQT;
    const int ktiles = 2 * qt + 2;

    const int r0 = tid >> 3,         c0 = (tid & 7) ^ (r0 & 7);
    const int r1 = (tid + 256) >> 3, c1 = (tid & 7) ^ (r1 & 7);

    bf16x8 qf[2][2];
#pragma unroll
    for (int ni = 0; ni < 2; ni++) {
        const unsigned short* qrow = Qb + (bh * SEQT + q0 + wave * 32 + ni * 16 + col) * HDIM;
        qf[ni][0] = *(const bf16x8*)(qrow + quad * 8);
        qf[ni][1] = *(const bf16x8*)(qrow + 32 + quad * 8);
    }

    GLD_LDS16(Kbh + r0 * HDIM + c0 * 8,        &K_lds[0][0] + tid * 8);
    GLD_LDS16(Kbh + r1 * HDIM + c1 * 8,        &K_lds[0][0] + 2048 + tid * 8);
    GLD_LDS16(Vbh + (long)r0 * SEQT + c0 * 8,  &V_lds[0][0] + tid * 8);
    GLD_LDS16(Vbh + (long)r1 * SEQT + c1 * 8,  &V_lds[0][0] + 2048 + tid * 8);

    f32x4 o[2][4];
#pragma unroll
    for (int mi = 0; mi < 2; mi++)
#pragma unroll
        for (int dt = 0; dt < 4; dt++) o[mi][dt] = (f32x4){0.f, 0.f, 0.f, 0.f};
    float rs[2] = {0.f, 0.f};

    const int cswz0 = quad ^ (col & 7);
    const int cswz1 = (quad + 4) ^ (col & 7);

    for (int kt = 0; kt < ktiles; kt++) {
        const int cur = kt & 1;
        __builtin_amdgcn_s_waitcnt(0x0F70);   // vmcnt(0)
        __syncthreads();
        if (kt + 1 < ktiles) {
            const int k0n = (kt + 1) * 64, nxt = cur ^ 1;
            GLD_LDS16(Kbh + (k0n + r0) * HDIM + c0 * 8,       &K_lds[nxt][0] + tid * 8);
            GLD_LDS16(Kbh + (k0n + r1) * HDIM + c1 * 8,       &K_lds[nxt][0] + 2048 + tid * 8);
            GLD_LDS16(Vbh + (long)r0 * SEQT + k0n + c0 * 8,   &V_lds[nxt][0] + tid * 8);
            GLD_LDS16(Vbh + (long)r1 * SEQT + k0n + c1 * 8,   &V_lds[nxt][0] + 2048 + tid * 8);
        }

        // S^T = K Q^T : A = K (m=key), B = Q (n=query). C: col=q, row=key.
        const unsigned short* Kc = &K_lds[cur][0];
        f32x4 st[4][2];
#pragma unroll
        for (int mt = 0; mt < 4; mt++) {
            const int row = mt * 16 + col;
            bf16x8 kf0 = *(const bf16x8*)&Kc[row * 64 + cswz0 * 8];
            bf16x8 kf1 = *(const bf16x8*)&Kc[row * 64 + cswz1 * 8];
#pragma unroll
            for (int ni = 0; ni < 2; ni++) {
                f32x4 acc = (f32x4){0.f, 0.f, 0.f, 0.f};
                acc = __builtin_amdgcn_mfma_f32_16x16x32_bf16(kf0, qf[ni][0], acc, 0, 0, 0);
                acc = __builtin_amdgcn_mfma_f32_16x16x32_bf16(kf1, qf[ni][1], acc, 0, 0, 0);
                st[mt][ni] = acc;
            }
        }
        const int k0 = kt * 64;
        if (kt >= 2 * qt) {                // diagonal tiles: mask key > q
#pragma unroll
            for (int mt = 0; mt < 4; mt++) {
                const int keybase = k0 + mt * 16 + quad * 4;
#pragma unroll
                for (int ni = 0; ni < 2; ni++) {
                    const int qg = q0 + wave * 32 + ni * 16 + col;
#pragma unroll
                    for (int r = 0; r < 4; r++)
                        if (keybase + r > qg) st[mt][ni][r] = -INFINITY;
                }
            }
        }

        // p = exp2(s); accumulate row-sum partials; packed b64 P-store
#pragma unroll
        for (int mt = 0; mt < 4; mt++)
#pragma unroll
            for (int ni = 0; ni < 2; ni++) {
                f32x4 p;
#pragma unroll
                for (int r = 0; r < 4; r++) p[r] = __builtin_amdgcn_exp2f(st[mt][ni][r]);
                rs[ni] += (p[0] + p[1]) + (p[2] + p[3]);
                bf16x4 pb = __builtin_convertvector(p, bf16x4);
                *(bf16x4*)&P_lds[(wave * 32 + ni * 16 + col) * PPAD + mt * 16 + quad * 4] = pb;
            }

        // PV: A = P[q][k] (wave-private rows), B = V^T
        const unsigned short* Vc = &V_lds[cur][0];
#pragma unroll
        for (int mi = 0; mi < 2; mi++) {
            const unsigned short* prow = &P_lds[(wave * 32 + mi * 16 + col) * PPAD];
            bf16x8 pf0 = *(const bf16x8*)(prow + quad * 8);
            bf16x8 pf1 = *(const bf16x8*)(prow + 32 + quad * 8);
#pragma unroll
            for (int dt = 0; dt < 4; dt++) {
                const int row = dt * 16 + col;
                bf16x8 vf0 = *(const bf16x8*)&Vc[row * 64 + cswz0 * 8];
                bf16x8 vf1 = *(const bf16x8*)&Vc[row * 64 + cswz1 * 8];
                o[mi][dt] = __builtin_amdgcn_mfma_f32_16x16x32_bf16(pf0, vf0, o[mi][dt], 0, 0, 0);
                o[mi][dt] = __builtin_amdgcn_mfma_f32_16x16x32_bf16(pf1, vf1, o[mi][dt], 0, 0, 0);
            }
        }
    }

    // final row-sum reduction over quads (partials partitioned by quad)
#pragma unroll
    for (int ni = 0; ni < 2; ni++) {
        rs[ni] += __shfl_xor(rs[ni], 16);
        rs[ni] += __shfl_xor(rs[ni], 32);
        if (quad == 0) L_lds[wave * 32 + ni * 16 + col] = rs[ni];
    }
    __syncthreads();
    f32x4 lf[2];
#pragma unroll
    for (int mi = 0; mi < 2; mi++)
        lf[mi] = *(const f32x4*)&L_lds[wave * 32 + mi * 16 + quad * 4];

    // epilogue: bf16 Ob[b][t][h*64+d]
#pragma unroll
    for (int mi = 0; mi < 2; mi++)
#pragma unroll
        for (int r = 0; r < 4; r++) {
            float inv = 1.f / lf[mi][r];
            int t = q0 + wave * 32 + mi * 16 + quad * 4 + r;
            unsigned short* orow = Ob + ((long)(b * SEQT + t)) * EMBED + h * HDIM;
#pragma unroll
            for (int dt = 0; dt < 4; dt++)
                orow[dt * 16 + col] = f2bf_hw(o[mi][dt][r] * inv);
        }
}

extern "C" void kernel_launch(void* const* d_in, const int* in_sizes, int n_in,
                              void* d_out, int out_size, void* d_ws, size_t ws_size,
                              hipStream_t stream)
{
    const float* x     = (const float*)d_in[0];
    const float* Wqkv  = (const float*)d_in[1];
    const float* bqkv  = (const float*)d_in[2];
    const float* Wproj = (const float*)d_in[3];
    const float* bproj = (const float*)d_in[4];
    float* out = (float*)d_out;

    const long Mbt = (long)BATCH * SEQT;                 // 8192
    const long per = (long)BATCH * NHEAD * SEQT * HDIM;  // 8,388,608 elems

    unsigned short* xb  = (unsigned short*)d_ws;
    unsigned short* wqb = xb  + per;
    unsigned short* wpb = wqb + 3 * EMBED * EMBED;
    unsigned short* Qb  = wpb + EMBED * EMBED;           // bf16 [bh][t][d], pre-scaled
    unsigned short* Kb  = Qb + per;
    unsigned short* Vt  = Kb + per;                      // bf16 [bh][d][t]
    unsigned short* Ob  = Vt + per;                      // bf16 [B,T,C]

    cvt_all<<<12288, 256, 0, stream>>>(x, Wqkv, Wproj, xb, wqb, wpb);

    dim3 g1(3 * EMBED / 256, Mbt / 256);                 // 12 x 32 = 384 blocks
    gemm_bt_m201<1><<<g1, 512, 0, stream>>>(xb, wqb, bqkv, Qb, Kb, Vt,
                                            (int)Mbt, 3 * EMBED);

    flash_attn_mfma4<<<1024, 256, 0, stream>>>(Qb, Kb, Vt, Ob);

    dim3 g3(EMBED / 256, Mbt / 256);                     // 4 x 32 = 128 blocks
    gemm_bt_m201<0><<<g3, 512, 0, stream>>>(Ob, wpb, bproj, out, nullptr, nullptr,
                                            (int)Mbt, EMBED);
}

// Round 4
// 258.143 us; speedup vs baseline: 1.0906x; 1.0906x over previous
//
#include <hip/hip_runtime.h>
#include <math.h>

#define EMBED 1024
#define NHEAD 16
#define HDIM  64
#define SEQT  2048
#define BATCH 4

typedef __bf16 bf16x4 __attribute__((ext_vector_type(4)));
typedef __bf16 bf16x8 __attribute__((ext_vector_type(8)));
typedef float  f32x4  __attribute__((ext_vector_type(4)));

#define AS1 __attribute__((address_space(1)))
#define AS3 __attribute__((address_space(3)))
// async global->LDS, 16B per lane (guide §5: width=16, m97-verified)
#define GLD_LDS16(gp, lp) __builtin_amdgcn_global_load_lds( \
    (const AS1 unsigned int*)(gp), (AS3 unsigned int*)(lp), 16, 0, 0)

// log2(e) / sqrt(HDIM): folded into Q at QKV-epilogue so scores are exp2-ready
#define QSCALE 0.180336880f

// native cast (v_cvt_pk_bf16_f32 on gfx950)
__device__ __forceinline__ unsigned short f2bf_hw(float f) {
    union { __bf16 h; unsigned short u; } c; c.h = (__bf16)f; return c.u;
}

// one launch converts x, W_qkv, W_proj (fp32 -> bf16), in float4 units
__global__ __launch_bounds__(256)
void cvt_all(const float* __restrict__ x, const float* __restrict__ wq,
             const float* __restrict__ wp,
             unsigned short* __restrict__ xb, unsigned short* __restrict__ wqb,
             unsigned short* __restrict__ wpb)
{
    const int N1 = 2097152;            // 8192*1024/4
    const int N2 = 786432;             // 3*1024*1024/4
    int i = blockIdx.x * 256 + threadIdx.x;
    const float4* src; ushort4* dst; int j;
    if (i < N1)            { src = (const float4*)x;  dst = (ushort4*)xb;  j = i; }
    else if (i < N1 + N2)  { src = (const float4*)wq; dst = (ushort4*)wqb; j = i - N1; }
    else                   { src = (const float4*)wp; dst = (ushort4*)wpb; j = i - N1 - N2; }
    float4 v = src[j];
    ushort4 o;
    o.x = f2bf_hw(v.x); o.y = f2bf_hw(v.y); o.z = f2bf_hw(v.z); o.w = f2bf_hw(v.w);
    dst[j] = o;
}

// ---------------- bf16 MFMA GEMM (R0 structure + LDS conflict swizzle) ----------
// C[m,n] = sum_k A[m,k]*Bw[n,k] + bias[n].  128x128 tile, BK=32, 2x2 waves,
// each wave 4x4 accs of 16x16x32. K-tile k+1 async-staged (global_load_lds)
// into the alternate LDS buffer while tile k computes; ONE barrier per iter.
// CONFLICT FIX (R0 measured 6.29M = 4 extra cyc per ds_read_b128): rows are
// 64B = 4 x 16B slots; physical slot = logical ^ ((row>>1)&3), so the bank
// group (row&1)*4 + slot is a bijection over 8 groups per 8 rows -> 2
// lanes/group (free, m136). Applied via pre-swizzled GLOBAL source (rule #21;
// LDS dest stays linear) + matching read-side slot quad ^ ((col>>1)&3).
// Row+64 keeps (row>>1)&3, so one source base serves both 64-row groups.
template<int MODE>
__global__ __launch_bounds__(256)
void gemm_bt_mfma(const unsigned short* __restrict__ A, const unsigned short* __restrict__ Bw,
                  const float* __restrict__ bias,
                  void* out0, void* out1, void* out2,
                  int M, int N, int K)
{
    __shared__ __align__(16) unsigned short Asm[2][128 * 32];   // 16 KB
    __shared__ __align__(16) unsigned short Bsm[2][128 * 32];   // 16 KB

    const int tid  = threadIdx.x;
    const int lane = tid & 63;
    const int wave = tid >> 6;
    const int wm = wave >> 1, wn = wave & 1;
    const int col = lane & 15, quad = lane >> 4;
    const long m0 = (long)blockIdx.y * 128, n0 = (long)blockIdx.x * 128;

    f32x4 acc[4][4];
#pragma unroll
    for (int mi = 0; mi < 4; mi++)
#pragma unroll
        for (int ni = 0; ni < 4; ni++) acc[mi][ni] = (f32x4){0.f, 0.f, 0.f, 0.f};

    const int lrow = tid >> 2;          // 0..63
    // source slot pre-swizzled: (tid&3) ^ ((row>>1)&3), row = tid>>2
    const int lcol = ((tid & 3) ^ ((tid >> 3) & 3)) * 8;
    const unsigned short* Ag = A + (m0 + lrow) * K + lcol;
    const unsigned short* Bg = Bw + (n0 + lrow) * K + lcol;

    // read-side physical slot for logical slots quad (rows r: (r>>1)&3 == (col>>1)&3)
    const int rsw = (quad ^ ((col >> 1) & 3)) * 8;

    // preload K-tile 0 into buffer 0
    GLD_LDS16(Ag,                &Asm[0][0] + tid * 8);
    GLD_LDS16(Ag + (long)64 * K, &Asm[0][0] + 2048 + tid * 8);
    GLD_LDS16(Bg,                &Bsm[0][0] + tid * 8);
    GLD_LDS16(Bg + (long)64 * K, &Bsm[0][0] + 2048 + tid * 8);

    const int iters = K >> 5;
    for (int it = 0; it < iters; it++) {
        const int cur = it & 1;
        __builtin_amdgcn_s_waitcnt(0x0F70);   // vmcnt(0): tile `it` staged
        __syncthreads();                      // all waves done reading buf[cur] (prev gen)
        if (it + 1 < iters) {                 // stage tile it+1 into other buffer
            const int kk = (it + 1) * 32, nxt = cur ^ 1;
            GLD_LDS16(Ag + kk,                &Asm[nxt][0] + tid * 8);
            GLD_LDS16(Ag + (long)64 * K + kk, &Asm[nxt][0] + 2048 + tid * 8);
            GLD_LDS16(Bg + kk,                &Bsm[nxt][0] + tid * 8);
            GLD_LDS16(Bg + (long)64 * K + kk, &Bsm[nxt][0] + 2048 + tid * 8);
        }

        bf16x8 af[4], bf[4];
#pragma unroll
        for (int mi = 0; mi < 4; mi++)
            af[mi] = *(const bf16x8*)&Asm[cur][(wm * 64 + mi * 16 + col) * 32 + rsw];
#pragma unroll
        for (int ni = 0; ni < 4; ni++)
            bf[ni] = *(const bf16x8*)&Bsm[cur][(wn * 64 + ni * 16 + col) * 32 + rsw];
#pragma unroll
        for (int mi = 0; mi < 4; mi++)
#pragma unroll
            for (int ni = 0; ni < 4; ni++)
                acc[mi][ni] = __builtin_amdgcn_mfma_f32_16x16x32_bf16(af[mi], bf[ni], acc[mi][ni], 0, 0, 0);
    }

    // epilogue: C/D layout col=lane&15, row=quad*4+r (m89/m91-verified)
#pragma unroll
    for (int mi = 0; mi < 4; mi++) {
#pragma unroll
        for (int ni = 0; ni < 4; ni++) {
            long n = n0 + wn * 64 + ni * 16 + col;
            float bv = bias[n];
#pragma unroll
            for (int r = 0; r < 4; r++) {
                long m = m0 + wm * 64 + mi * 16 + quad * 4 + r;
                float v = acc[mi][ni][r] + bv;
                if (MODE == 0) {
                    ((float*)out0)[m * N + n] = v;
                } else {
                    int which = (int)(n >> 10);
                    int c = (int)(n & 1023);
                    int h = c >> 6, d = c & 63;
                    int b = (int)(m >> 11), t = (int)(m & 2047);
                    long bh = (long)(b * NHEAD + h);
                    if (which == 0)      ((unsigned short*)out0)[(bh * SEQT + t) * HDIM + d] = f2bf_hw(v * QSCALE);
                    else if (which == 1) ((unsigned short*)out1)[(bh * SEQT + t) * HDIM + d] = f2bf_hw(v);
                    else                 ((unsigned short*)out2)[(bh * HDIM + d) * SEQT + t] = f2bf_hw(v);
                }
            }
        }
    }
}

// ---------------- bf16 MFMA flash attention (R0 v4 + T5 setprio) ----------------
// Q-tile 128; 4 waves × 32 q-rows. No-max softmax; S computed transposed
// (mfma(K,Q)) -> packed b64 P stores; P stored [q][k] for b128 PV A-frag reads.
// T5: setprio(1) around QK and PV MFMA clusters — regime matches m191's
// positive case (3 independent blocks/CU at different phases, not lockstep).
#define PPAD 72

__global__ __launch_bounds__(256, 3)
void flash_attn_mfma4(const unsigned short* __restrict__ Qb,
                      const unsigned short* __restrict__ Kb,
                      const unsigned short* __restrict__ Vt,
                      unsigned short* __restrict__ Ob)
{
    __shared__ __align__(16) unsigned short P_lds[128 * PPAD];    // [q][k] 18432 B
    __shared__ __align__(16) unsigned short K_lds[2][64 * 64];    // 16 KB
    __shared__ __align__(16) unsigned short V_lds[2][64 * 64];    // 16 KB
    __shared__ __align__(16) float L_lds[128];                    // row sums

    const int tid  = threadIdx.x;
    const int lane = tid & 63;
    const int wave = tid >> 6;
    const int col  = lane & 15;
    const int quad = lane >> 4;

    const int idx = blockIdx.x;
    const int qt = 15 - (idx >> 6);      // longest blocks dispatched first
    const int hb = idx & 63;
    const int h = hb & 15, b = hb >> 4;
    const int q0 = qt * 128;
    const long bh = (long)(b * NHEAD + h);
    const unsigned short* Kbh = Kb + bh * SEQT * HDIM;
    const unsigned short* Vbh = Vt + bh * HDIM * SEQT;
    const int ktiles = 2 * qt + 2;

    const int r0 = tid >> 3,         c0 = (tid & 7) ^ (r0 & 7);
    const int r1 = (tid + 256) >> 3, c1 = (tid & 7) ^ (r1 & 7);

    bf16x8 qf[2][2];
#pragma unroll
    for (int ni = 0; ni < 2; ni++) {
        const unsigned short* qrow = Qb + (bh * SEQT + q0 + wave * 32 + ni * 16 + col) * HDIM;
        qf[ni][0] = *(const bf16x8*)(qrow + quad * 8);
        qf[ni][1] = *(const bf16x8*)(qrow + 32 + quad * 8);
    }

    GLD_LDS16(Kbh + r0 * HDIM + c0 * 8,        &K_lds[0][0] + tid * 8);
    GLD_LDS16(Kbh + r1 * HDIM + c1 * 8,        &K_lds[0][0] + 2048 + tid * 8);
    GLD_LDS16(Vbh + (long)r0 * SEQT + c0 * 8,  &V_lds[0][0] + tid * 8);
    GLD_LDS16(Vbh + (long)r1 * SEQT + c1 * 8,  &V_lds[0][0] + 2048 + tid * 8);

    f32x4 o[2][4];
#pragma unroll
    for (int mi = 0; mi < 2; mi++)
#pragma unroll
        for (int dt = 0; dt < 4; dt++) o[mi][dt] = (f32x4){0.f, 0.f, 0.f, 0.f};
    float rs[2] = {0.f, 0.f};

    const int cswz0 = quad ^ (col & 7);
    const int cswz1 = (quad + 4) ^ (col & 7);

    for (int kt = 0; kt < ktiles; kt++) {
        const int cur = kt & 1;
        __builtin_amdgcn_s_waitcnt(0x0F70);   // vmcnt(0)
        __syncthreads();
        if (kt + 1 < ktiles) {
            const int k0n = (kt + 1) * 64, nxt = cur ^ 1;
            GLD_LDS16(Kbh + (k0n + r0) * HDIM + c0 * 8,       &K_lds[nxt][0] + tid * 8);
            GLD_LDS16(Kbh + (k0n + r1) * HDIM + c1 * 8,       &K_lds[nxt][0] + 2048 + tid * 8);
            GLD_LDS16(Vbh + (long)r0 * SEQT + k0n + c0 * 8,   &V_lds[nxt][0] + tid * 8);
            GLD_LDS16(Vbh + (long)r1 * SEQT + k0n + c1 * 8,   &V_lds[nxt][0] + 2048 + tid * 8);
        }

        // S^T = K Q^T : A = K (m=key), B = Q (n=query). C: col=q, row=key.
        const unsigned short* Kc = &K_lds[cur][0];
        f32x4 st[4][2];
        __builtin_amdgcn_s_setprio(1);
#pragma unroll
        for (int mt = 0; mt < 4; mt++) {
            const int row = mt * 16 + col;
            bf16x8 kf0 = *(const bf16x8*)&Kc[row * 64 + cswz0 * 8];
            bf16x8 kf1 = *(const bf16x8*)&Kc[row * 64 + cswz1 * 8];
#pragma unroll
            for (int ni = 0; ni < 2; ni++) {
                f32x4 acc = (f32x4){0.f, 0.f, 0.f, 0.f};
                acc = __builtin_amdgcn_mfma_f32_16x16x32_bf16(kf0, qf[ni][0], acc, 0, 0, 0);
                acc = __builtin_amdgcn_mfma_f32_16x16x32_bf16(kf1, qf[ni][1], acc, 0, 0, 0);
                st[mt][ni] = acc;
            }
        }
        __builtin_amdgcn_s_setprio(0);
        const int k0 = kt * 64;
        if (kt >= 2 * qt) {                // diagonal tiles: mask key > q
#pragma unroll
            for (int mt = 0; mt < 4; mt++) {
                const int keybase = k0 + mt * 16 + quad * 4;
#pragma unroll
                for (int ni = 0; ni < 2; ni++) {
                    const int qg = q0 + wave * 32 + ni * 16 + col;
#pragma unroll
                    for (int r = 0; r < 4; r++)
                        if (keybase + r > qg) st[mt][ni][r] = -INFINITY;
                }
            }
        }

        // p = exp2(s); accumulate row-sum partials; packed b64 P-store
#pragma unroll
        for (int mt = 0; mt < 4; mt++)
#pragma unroll
            for (int ni = 0; ni < 2; ni++) {
                f32x4 p;
#pragma unroll
                for (int r = 0; r < 4; r++) p[r] = __builtin_amdgcn_exp2f(st[mt][ni][r]);
                rs[ni] += (p[0] + p[1]) + (p[2] + p[3]);
                bf16x4 pb = __builtin_convertvector(p, bf16x4);
                *(bf16x4*)&P_lds[(wave * 32 + ni * 16 + col) * PPAD + mt * 16 + quad * 4] = pb;
            }

        // PV: A = P[q][k] (wave-private rows), B = V^T
        const unsigned short* Vc = &V_lds[cur][0];
        __builtin_amdgcn_s_setprio(1);
#pragma unroll
        for (int mi = 0; mi < 2; mi++) {
            const unsigned short* prow = &P_lds[(wave * 32 + mi * 16 + col) * PPAD];
            bf16x8 pf0 = *(const bf16x8*)(prow + quad * 8);
            bf16x8 pf1 = *(const bf16x8*)(prow + 32 + quad * 8);
#pragma unroll
            for (int dt = 0; dt < 4; dt++) {
                const int row = dt * 16 + col;
                bf16x8 vf0 = *(const bf16x8*)&Vc[row * 64 + cswz0 * 8];
                bf16x8 vf1 = *(const bf16x8*)&Vc[row * 64 + cswz1 * 8];
                o[mi][dt] = __builtin_amdgcn_mfma_f32_16x16x32_bf16(pf0, vf0, o[mi][dt], 0, 0, 0);
                o[mi][dt] = __builtin_amdgcn_mfma_f32_16x16x32_bf16(pf1, vf1, o[mi][dt], 0, 0, 0);
            }
        }
        __builtin_amdgcn_s_setprio(0);
    }

    // final row-sum reduction over quads (partials partitioned by quad)
#pragma unroll
    for (int ni = 0; ni < 2; ni++) {
        rs[ni] += __shfl_xor(rs[ni], 16);
        rs[ni] += __shfl_xor(rs[ni], 32);
        if (quad == 0) L_lds[wave * 32 + ni * 16 + col] = rs[ni];
    }
    __syncthreads();
    f32x4 lf[2];
#pragma unroll
    for (int mi = 0; mi < 2; mi++)
        lf[mi] = *(const f32x4*)&L_lds[wave * 32 + mi * 16 + quad * 4];

    // epilogue: bf16 Ob[b][t][h*64+d]
#pragma unroll
    for (int mi = 0; mi < 2; mi++)
#pragma unroll
        for (int r = 0; r < 4; r++) {
            float inv = 1.f / lf[mi][r];
            int t = q0 + wave * 32 + mi * 16 + quad * 4 + r;
            unsigned short* orow = Ob + ((long)(b * SEQT + t)) * EMBED + h * HDIM;
#pragma unroll
            for (int dt = 0; dt < 4; dt++)
                orow[dt * 16 + col] = f2bf_hw(o[mi][dt][r] * inv);
        }
}

extern "C" void kernel_launch(void* const* d_in, const int* in_sizes, int n_in,
                              void* d_out, int out_size, void* d_ws, size_t ws_size,
                              hipStream_t stream)
{
    const float* x     = (const float*)d_in[0];
    const float* Wqkv  = (const float*)d_in[1];
    const float* bqkv  = (const float*)d_in[2];
    const float* Wproj = (const float*)d_in[3];
    const float* bproj = (const float*)d_in[4];
    float* out = (float*)d_out;

    const long Mbt = (long)BATCH * SEQT;                 // 8192
    const long per = (long)BATCH * NHEAD * SEQT * HDIM;  // 8,388,608 elems

    unsigned short* xb  = (unsigned short*)d_ws;
    unsigned short* wqb = xb  + per;
    unsigned short* wpb = wqb + 3 * EMBED * EMBED;
    unsigned short* Qb  = wpb + EMBED * EMBED;           // bf16 [bh][t][d], pre-scaled
    unsigned short* Kb  = Qb + per;
    unsigned short* Vt  = Kb + per;                      // bf16 [bh][d][t]
    unsigned short* Ob  = Vt + per;                      // bf16 [B,T,C]

    cvt_all<<<12288, 256, 0, stream>>>(x, Wqkv, Wproj, xb, wqb, wpb);

    dim3 g1(3 * EMBED / 128, Mbt / 128);
    gemm_bt_mfma<1><<<g1, 256, 0, stream>>>(xb, wqb, bqkv, Qb, Kb, Vt,
                                            (int)Mbt, 3 * EMBED, EMBED);

    flash_attn_mfma4<<<1024, 256, 0, stream>>>(Qb, Kb, Vt, Ob);

    dim3 g3(EMBED / 128, Mbt / 128);
    gemm_bt_mfma<0><<<g3, 256, 0, stream>>>(Ob, wpb, bproj, out, nullptr, nullptr,
                                            (int)Mbt, EMBED, EMBED);
}

// Round 5
// 250.724 us; speedup vs baseline: 1.1229x; 1.0296x over previous
//
#include <hip/hip_runtime.h>
#include <math.h>

#define EMBED 1024
#define NHEAD 16
#define HDIM  64
#define SEQT  2048
#define BATCH 4

typedef __bf16 bf16x4 __attribute__((ext_vector_type(4)));
typedef __bf16 bf16x8 __attribute__((ext_vector_type(8)));
typedef float  f32x4  __attribute__((ext_vector_type(4)));

#define AS1 __attribute__((address_space(1)))
#define AS3 __attribute__((address_space(3)))
// async global->LDS, 16B per lane (guide §5: width=16, m97-verified)
#define GLD_LDS16(gp, lp) __builtin_amdgcn_global_load_lds( \
    (const AS1 unsigned int*)(gp), (AS3 unsigned int*)(lp), 16, 0, 0)

// log2(e) / sqrt(HDIM): folded into Q at QKV-epilogue so scores are exp2-ready
#define QSCALE 0.180336880f

// native cast (v_cvt_pk_bf16_f32 on gfx950)
__device__ __forceinline__ unsigned short f2bf_hw(float f) {
    union { __bf16 h; unsigned short u; } c; c.h = (__bf16)f; return c.u;
}

// one launch converts x, W_qkv, W_proj (fp32 -> bf16), in float4 units
__global__ __launch_bounds__(256)
void cvt_all(const float* __restrict__ x, const float* __restrict__ wq,
             const float* __restrict__ wp,
             unsigned short* __restrict__ xb, unsigned short* __restrict__ wqb,
             unsigned short* __restrict__ wpb)
{
    const int N1 = 2097152;            // 8192*1024/4
    const int N2 = 786432;             // 3*1024*1024/4
    int i = blockIdx.x * 256 + threadIdx.x;
    const float4* src; ushort4* dst; int j;
    if (i < N1)            { src = (const float4*)x;  dst = (ushort4*)xb;  j = i; }
    else if (i < N1 + N2)  { src = (const float4*)wq; dst = (ushort4*)wqb; j = i - N1; }
    else                   { src = (const float4*)wp; dst = (ushort4*)wpb; j = i - N1 - N2; }
    float4 v = src[j];
    ushort4 o;
    o.x = f2bf_hw(v.x); o.y = f2bf_hw(v.y); o.z = f2bf_hw(v.z); o.w = f2bf_hw(v.w);
    dst[j] = o;
}

// ---------------- bf16 MFMA GEMM (R0 skeleton, BK=64) ----------------
// C[m,n] = sum_k A[m,k]*Bw[n,k] + bias[n].  128x128 tile, BK=64, 2x2 waves,
// each wave 4x4 accs of 16x16x32 (x2 K-slices). Same 2-phase barrier skeleton
// as R0 (proven 545 TF) but HALF the sync events: 16 iters x (vmcnt(0)+barrier)
// instead of 32 — R4 proved conflicts were off the critical path; m233 says
// the per-iteration drain+barrier is the ~72% overhead, so amortize it.
// LDS 64KB -> 2 blocks/CU (= the effective occupancy R0 already had).
// Rows are 128B = 8 x 16B slots: read slot (ks*4+quad) ^ (col&7) -> 8 lanes
// per slot = balanced floor; staging pre-swizzles the GLOBAL source slot
// (tid&7)^((tid>>3)&7) (rule #21: LDS dest stays linear), invariant under
// row+32 so one base serves all 4 row-groups.
template<int MODE>
__global__ __launch_bounds__(256)
void gemm_bt_mfma(const unsigned short* __restrict__ A, const unsigned short* __restrict__ Bw,
                  const float* __restrict__ bias,
                  void* out0, void* out1, void* out2,
                  int M, int N, int K)
{
    __shared__ __align__(16) unsigned short Asm[2][128 * 64];   // 2 x 16 KB
    __shared__ __align__(16) unsigned short Bsm[2][128 * 64];   // 2 x 16 KB

    const int tid  = threadIdx.x;
    const int lane = tid & 63;
    const int wave = tid >> 6;
    const int wm = wave >> 1, wn = wave & 1;
    const int col = lane & 15, quad = lane >> 4;
    const long m0 = (long)blockIdx.y * 128, n0 = (long)blockIdx.x * 128;

    f32x4 acc[4][4];
#pragma unroll
    for (int mi = 0; mi < 4; mi++)
#pragma unroll
        for (int ni = 0; ni < 4; ni++) acc[mi][ni] = (f32x4){0.f, 0.f, 0.f, 0.f};

    // staging: 4 calls per matrix per K-tile; call r covers rows r*32 + (tid>>3)
    const int srow  = tid >> 3;                    // 0..31
    const int gslot = (tid & 7) ^ (srow & 7);      // pre-swizzled source slot
    const unsigned short* Ag = A  + (m0 + srow) * K + gslot * 8;
    const unsigned short* Bg = Bw + (n0 + srow) * K + gslot * 8;

#define STAGE(buf_, kk_) do { \
    _Pragma("unroll") for (int r_ = 0; r_ < 4; r_++) { \
        GLD_LDS16(Ag + (long)(r_ * 32) * K + (kk_), &Asm[buf_][0] + r_ * 2048 + tid * 8); \
        GLD_LDS16(Bg + (long)(r_ * 32) * K + (kk_), &Bsm[buf_][0] + r_ * 2048 + tid * 8); \
    } } while (0)

    // read-side physical slots (element offsets): logical slot ks*4+quad,
    // phys = logical ^ (row&7), row&7 == col&7 (rows are 16-aligned + col)
    const int cs0 = ((quad    ) ^ (col & 7)) * 8;  // K-slice 0
    const int cs1 = ((quad + 4) ^ (col & 7)) * 8;  // K-slice 1

    // preload K-tile 0 into buffer 0
    STAGE(0, 0);

    const int iters = K >> 6;
    for (int it = 0; it < iters; it++) {
        const int cur = it & 1;
        __builtin_amdgcn_s_waitcnt(0x0F70);   // vmcnt(0): tile `it` staged
        __syncthreads();                      // all waves done reading buf[cur] (prev gen)
        if (it + 1 < iters)                   // stage tile it+1 into other buffer
            STAGE(cur ^ 1, (it + 1) * 64);

        bf16x8 af[4][2], bf[4][2];
#pragma unroll
        for (int mi = 0; mi < 4; mi++) {
            const int row = wm * 64 + mi * 16 + col;
            af[mi][0] = *(const bf16x8*)&Asm[cur][row * 64 + cs0];
            af[mi][1] = *(const bf16x8*)&Asm[cur][row * 64 + cs1];
        }
#pragma unroll
        for (int ni = 0; ni < 4; ni++) {
            const int row = wn * 64 + ni * 16 + col;
            bf[ni][0] = *(const bf16x8*)&Bsm[cur][row * 64 + cs0];
            bf[ni][1] = *(const bf16x8*)&Bsm[cur][row * 64 + cs1];
        }
#pragma unroll
        for (int mi = 0; mi < 4; mi++)
#pragma unroll
            for (int ni = 0; ni < 4; ni++) {
                acc[mi][ni] = __builtin_amdgcn_mfma_f32_16x16x32_bf16(af[mi][0], bf[ni][0], acc[mi][ni], 0, 0, 0);
                acc[mi][ni] = __builtin_amdgcn_mfma_f32_16x16x32_bf16(af[mi][1], bf[ni][1], acc[mi][ni], 0, 0, 0);
            }
    }
#undef STAGE

    // epilogue: C/D layout col=lane&15, row=quad*4+r (m89/m91-verified)
#pragma unroll
    for (int mi = 0; mi < 4; mi++) {
#pragma unroll
        for (int ni = 0; ni < 4; ni++) {
            long n = n0 + wn * 64 + ni * 16 + col;
            float bv = bias[n];
#pragma unroll
            for (int r = 0; r < 4; r++) {
                long m = m0 + wm * 64 + mi * 16 + quad * 4 + r;
                float v = acc[mi][ni][r] + bv;
                if (MODE == 0) {
                    ((float*)out0)[m * N + n] = v;
                } else {
                    int which = (int)(n >> 10);
                    int c = (int)(n & 1023);
                    int h = c >> 6, d = c & 63;
                    int b = (int)(m >> 11), t = (int)(m & 2047);
                    long bh = (long)(b * NHEAD + h);
                    if (which == 0)      ((unsigned short*)out0)[(bh * SEQT + t) * HDIM + d] = f2bf_hw(v * QSCALE);
                    else if (which == 1) ((unsigned short*)out1)[(bh * SEQT + t) * HDIM + d] = f2bf_hw(v);
                    else                 ((unsigned short*)out2)[(bh * HDIM + d) * SEQT + t] = f2bf_hw(v);
                }
            }
        }
    }
}

// ---------------- bf16 MFMA flash attention (R4: v4 + T5 setprio) ----------------
// Q-tile 128; 4 waves × 32 q-rows. No-max softmax; S computed transposed
// (mfma(K,Q)) -> packed b64 P stores; P stored [q][k] for b128 PV A-frag reads.
#define PPAD 72

__global__ __launch_bounds__(256, 3)
void flash_attn_mfma4(const unsigned short* __restrict__ Qb,
                      const unsigned short* __restrict__ Kb,
                      const unsigned short* __restrict__ Vt,
                      unsigned short* __restrict__ Ob)
{
    __shared__ __align__(16) unsigned short P_lds[128 * PPAD];    // [q][k] 18432 B
    __shared__ __align__(16) unsigned short K_lds[2][64 * 64];    // 16 KB
    __shared__ __align__(16) unsigned short V_lds[2][64 * 64];    // 16 KB
    __shared__ __align__(16) float L_lds[128];                    // row sums

    const int tid  = threadIdx.x;
    const int lane = tid & 63;
    const int wave = tid >> 6;
    const int col  = lane & 15;
    const int quad = lane >> 4;

    const int idx = blockIdx.x;
    const int qt = 15 - (idx >> 6);      // longest blocks dispatched first
    const int hb = idx & 63;
    const int h = hb & 15, b = hb >> 4;
    const int q0 = qt * 128;
    const long bh = (long)(b * NHEAD + h);
    const unsigned short* Kbh = Kb + bh * SEQT * HDIM;
    const unsigned short* Vbh = Vt + bh * HDIM * SEQT;
    const int ktiles = 2 * qt + 2;

    const int r0 = tid >> 3,         c0 = (tid & 7) ^ (r0 & 7);
    const int r1 = (tid + 256) >> 3, c1 = (tid & 7) ^ (r1 & 7);

    bf16x8 qf[2][2];
#pragma unroll
    for (int ni = 0; ni < 2; ni++) {
        const unsigned short* qrow = Qb + (bh * SEQT + q0 + wave * 32 + ni * 16 + col) * HDIM;
        qf[ni][0] = *(const bf16x8*)(qrow + quad * 8);
        qf[ni][1] = *(const bf16x8*)(qrow + 32 + quad * 8);
    }

    GLD_LDS16(Kbh + r0 * HDIM + c0 * 8,        &K_lds[0][0] + tid * 8);
    GLD_LDS16(Kbh + r1 * HDIM + c1 * 8,        &K_lds[0][0] + 2048 + tid * 8);
    GLD_LDS16(Vbh + (long)r0 * SEQT + c0 * 8,  &V_lds[0][0] + tid * 8);
    GLD_LDS16(Vbh + (long)r1 * SEQT + c1 * 8,  &V_lds[0][0] + 2048 + tid * 8);

    f32x4 o[2][4];
#pragma unroll
    for (int mi = 0; mi < 2; mi++)
#pragma unroll
        for (int dt = 0; dt < 4; dt++) o[mi][dt] = (f32x4){0.f, 0.f, 0.f, 0.f};
    float rs[2] = {0.f, 0.f};

    const int cswz0 = quad ^ (col & 7);
    const int cswz1 = (quad + 4) ^ (col & 7);

    for (int kt = 0; kt < ktiles; kt++) {
        const int cur = kt & 1;
        __builtin_amdgcn_s_waitcnt(0x0F70);   // vmcnt(0)
        __syncthreads();
        if (kt + 1 < ktiles) {
            const int k0n = (kt + 1) * 64, nxt = cur ^ 1;
            GLD_LDS16(Kbh + (k0n + r0) * HDIM + c0 * 8,       &K_lds[nxt][0] + tid * 8);
            GLD_LDS16(Kbh + (k0n + r1) * HDIM + c1 * 8,       &K_lds[nxt][0] + 2048 + tid * 8);
            GLD_LDS16(Vbh + (long)r0 * SEQT + k0n + c0 * 8,   &V_lds[nxt][0] + tid * 8);
            GLD_LDS16(Vbh + (long)r1 * SEQT + k0n + c1 * 8,   &V_lds[nxt][0] + 2048 + tid * 8);
        }

        // S^T = K Q^T : A = K (m=key), B = Q (n=query). C: col=q, row=key.
        const unsigned short* Kc = &K_lds[cur][0];
        f32x4 st[4][2];
        __builtin_amdgcn_s_setprio(1);
#pragma unroll
        for (int mt = 0; mt < 4; mt++) {
            const int row = mt * 16 + col;
            bf16x8 kf0 = *(const bf16x8*)&Kc[row * 64 + cswz0 * 8];
            bf16x8 kf1 = *(const bf16x8*)&Kc[row * 64 + cswz1 * 8];
#pragma unroll
            for (int ni = 0; ni < 2; ni++) {
                f32x4 acc = (f32x4){0.f, 0.f, 0.f, 0.f};
                acc = __builtin_amdgcn_mfma_f32_16x16x32_bf16(kf0, qf[ni][0], acc, 0, 0, 0);
                acc = __builtin_amdgcn_mfma_f32_16x16x32_bf16(kf1, qf[ni][1], acc, 0, 0, 0);
                st[mt][ni] = acc;
            }
        }
        __builtin_amdgcn_s_setprio(0);
        const int k0 = kt * 64;
        if (kt >= 2 * qt) {                // diagonal tiles: mask key > q
#pragma unroll
            for (int mt = 0; mt < 4; mt++) {
                const int keybase = k0 + mt * 16 + quad * 4;
#pragma unroll
                for (int ni = 0; ni < 2; ni++) {
                    const int qg = q0 + wave * 32 + ni * 16 + col;
#pragma unroll
                    for (int r = 0; r < 4; r++)
                        if (keybase + r > qg) st[mt][ni][r] = -INFINITY;
                }
            }
        }

        // p = exp2(s); accumulate row-sum partials; packed b64 P-store
#pragma unroll
        for (int mt = 0; mt < 4; mt++)
#pragma unroll
            for (int ni = 0; ni < 2; ni++) {
                f32x4 p;
#pragma unroll
                for (int r = 0; r < 4; r++) p[r] = __builtin_amdgcn_exp2f(st[mt][ni][r]);
                rs[ni] += (p[0] + p[1]) + (p[2] + p[3]);
                bf16x4 pb = __builtin_convertvector(p, bf16x4);
                *(bf16x4*)&P_lds[(wave * 32 + ni * 16 + col) * PPAD + mt * 16 + quad * 4] = pb;
            }

        // PV: A = P[q][k] (wave-private rows), B = V^T
        const unsigned short* Vc = &V_lds[cur][0];
        __builtin_amdgcn_s_setprio(1);
#pragma unroll
        for (int mi = 0; mi < 2; mi++) {
            const unsigned short* prow = &P_lds[(wave * 32 + mi * 16 + col) * PPAD];
            bf16x8 pf0 = *(const bf16x8*)(prow + quad * 8);
            bf16x8 pf1 = *(const bf16x8*)(prow + 32 + quad * 8);
#pragma unroll
            for (int dt = 0; dt < 4; dt++) {
                const int row = dt * 16 + col;
                bf16x8 vf0 = *(const bf16x8*)&Vc[row * 64 + cswz0 * 8];
                bf16x8 vf1 = *(const bf16x8*)&Vc[row * 64 + cswz1 * 8];
                o[mi][dt] = __builtin_amdgcn_mfma_f32_16x16x32_bf16(pf0, vf0, o[mi][dt], 0, 0, 0);
                o[mi][dt] = __builtin_amdgcn_mfma_f32_16x16x32_bf16(pf1, vf1, o[mi][dt], 0, 0, 0);
            }
        }
        __builtin_amdgcn_s_setprio(0);
    }

    // final row-sum reduction over quads (partials partitioned by quad)
#pragma unroll
    for (int ni = 0; ni < 2; ni++) {
        rs[ni] += __shfl_xor(rs[ni], 16);
        rs[ni] += __shfl_xor(rs[ni], 32);
        if (quad == 0) L_lds[wave * 32 + ni * 16 + col] = rs[ni];
    }
    __syncthreads();
    f32x4 lf[2];
#pragma unroll
    for (int mi = 0; mi < 2; mi++)
        lf[mi] = *(const f32x4*)&L_lds[wave * 32 + mi * 16 + quad * 4];

    // epilogue: bf16 Ob[b][t][h*64+d]
#pragma unroll
    for (int mi = 0; mi < 2; mi++)
#pragma unroll
        for (int r = 0; r < 4; r++) {
            float inv = 1.f / lf[mi][r];
            int t = q0 + wave * 32 + mi * 16 + quad * 4 + r;
            unsigned short* orow = Ob + ((long)(b * SEQT + t)) * EMBED + h * HDIM;
#pragma unroll
            for (int dt = 0; dt < 4; dt++)
                orow[dt * 16 + col] = f2bf_hw(o[mi][dt][r] * inv);
        }
}

extern "C" void kernel_launch(void* const* d_in, const int* in_sizes, int n_in,
                              void* d_out, int out_size, void* d_ws, size_t ws_size,
                              hipStream_t stream)
{
    const float* x     = (const float*)d_in[0];
    const float* Wqkv  = (const float*)d_in[1];
    const float* bqkv  = (const float*)d_in[2];
    const float* Wproj = (const float*)d_in[3];
    const float* bproj = (const float*)d_in[4];
    float* out = (float*)d_out;

    const long Mbt = (long)BATCH * SEQT;                 // 8192
    const long per = (long)BATCH * NHEAD * SEQT * HDIM;  // 8,388,608 elems

    unsigned short* xb  = (unsigned short*)d_ws;
    unsigned short* wqb = xb  + per;
    unsigned short* wpb = wqb + 3 * EMBED * EMBED;
    unsigned short* Qb  = wpb + EMBED * EMBED;           // bf16 [bh][t][d], pre-scaled
    unsigned short* Kb  = Qb + per;
    unsigned short* Vt  = Kb + per;                      // bf16 [bh][d][t]
    unsigned short* Ob  = Vt + per;                      // bf16 [B,T,C]

    cvt_all<<<12288, 256, 0, stream>>>(x, Wqkv, Wproj, xb, wqb, wpb);

    dim3 g1(3 * EMBED / 128, Mbt / 128);
    gemm_bt_mfma<1><<<g1, 256, 0, stream>>>(xb, wqb, bqkv, Qb, Kb, Vt,
                                            (int)Mbt, 3 * EMBED, EMBED);

    flash_attn_mfma4<<<1024, 256, 0, stream>>>(Qb, Kb, Vt, Ob);

    dim3 g3(EMBED / 128, Mbt / 128);
    gemm_bt_mfma<0><<<g3, 256, 0, stream>>>(Ob, wpb, bproj, out, nullptr, nullptr,
                                            (int)Mbt, EMBED, EMBED);
}